// Round 16
// baseline (33.668 us; speedup 1.0000x reference)
//
#include <hip/hip_runtime.h>
#include <math.h>

#define NN 1024
#define MM 1024
#define DD 256
#define TI 32          // i-rows per block
#define TJ 64          // j-cols per block
#define NTI 32         // i-tiles (col-partial stripes)
#define NTJ 16         // j-tiles (row-partial stripes)
#define PITCH_H 264    // f16 pitch (528 B/row)

typedef _Float16 f16x2 __attribute__((ext_vector_type(2)));
typedef _Float16 f16x4 __attribute__((ext_vector_type(4)));

__device__ inline f16x2 habs2(f16x2 v) {
  unsigned u = __builtin_bit_cast(unsigned, v) & 0x7FFF7FFFu;
  return __builtin_bit_cast(f16x2, u);
}

__device__ inline void merge_ms(float& m, float& s, float m2, float s2) {
  float mn = fmaxf(m, m2);
  s = s * __expf(m - mn) + s2 * __expf(m2 - mn);
  m = mn;
}

__device__ inline float wredSum(float v) {
#pragma unroll
  for (int o = 32; o > 0; o >>= 1) v += __shfl_down(v, o, 64);
  return v;
}

// ---- K1: f16 distance, 32x64 tile, 512 blocks; packed-f16 accumulation ----
__global__ __launch_bounds__(256) void k_tile(const float* __restrict__ zx,
                                              const float* __restrict__ zy,
                                              float* __restrict__ S,
                                              float* __restrict__ rowPM,
                                              float* __restrict__ rowPS,
                                              float* __restrict__ colPM,
                                              float* __restrict__ colPS) {
  __shared__ __align__(16) _Float16 xs[TI * PITCH_H];  // 16.5 KiB
  __shared__ __align__(16) _Float16 ys[TJ * PITCH_H];  // 33 KiB
  __shared__ float lm[16][64];
  __shared__ float lsv[16][64];

  const int it = blockIdx.y, jt = blockIdx.x;   // it in [0,32), jt in [0,16)
  const int i0 = it * TI, j0 = jt * TJ;
  const int t = threadIdx.x;
  const int tx = t & 15, ty = t >> 4;

  // stage x: 32 rows x 256 f32 -> f16
#pragma unroll
  for (int k = 0; k < 8; ++k) {
    int idx4 = t + k * 256;
    int r = idx4 >> 6;
    int c4 = idx4 & 63;
    float4 v = reinterpret_cast<const float4*>(zx + (size_t)(i0 + r) * DD)[c4];
    f16x4 h = {(_Float16)v.x, (_Float16)v.y, (_Float16)v.z, (_Float16)v.w};
    *reinterpret_cast<f16x4*>(&xs[r * PITCH_H + c4 * 4]) = h;
  }
  // stage y: 64 rows x 256 f32 -> f16
#pragma unroll
  for (int k = 0; k < 16; ++k) {
    int idx4 = t + k * 256;
    int r = idx4 >> 6;
    int c4 = idx4 & 63;
    float4 v = reinterpret_cast<const float4*>(zy + (size_t)(j0 + r) * DD)[c4];
    f16x4 h = {(_Float16)v.x, (_Float16)v.y, (_Float16)v.z, (_Float16)v.w};
    *reinterpret_cast<f16x4*>(&ys[r * PITCH_H + c4 * 4]) = h;
  }
  __syncthreads();

  // packed-f16 accumulation: |d| summed in f16x2 (VOP3P pk ops, 3 instr/2 elems),
  // flushed to f32 every 2 steps (16 elems, partial sum small -> negligible error).
  float acc4[2][4] = {{0.f}};
  for (int s8 = 0; s8 < 32; s8 += 2) {
    f16x2 hacc[2][4];
#pragma unroll
    for (int a = 0; a < 2; ++a)
#pragma unroll
      for (int b = 0; b < 4; ++b) hacc[a][b] = (f16x2){(_Float16)0.0f, (_Float16)0.0f};

#pragma unroll
    for (int u = 0; u < 2; ++u) {
      const int s = s8 + u;
      uint4 xw[2], yw[4];
#pragma unroll
      for (int a = 0; a < 2; ++a)
        xw[a] = *reinterpret_cast<const uint4*>(&xs[(ty + a * 16) * PITCH_H + s * 8]);
#pragma unroll
      for (int b = 0; b < 4; ++b)
        yw[b] = *reinterpret_cast<const uint4*>(&ys[(tx + b * 16) * PITCH_H + s * 8]);
#pragma unroll
      for (int a = 0; a < 2; ++a)
#pragma unroll
        for (int b = 0; b < 4; ++b) {
          f16x2 h = hacc[a][b];
          h += habs2(__builtin_bit_cast(f16x2, xw[a].x) - __builtin_bit_cast(f16x2, yw[b].x));
          h += habs2(__builtin_bit_cast(f16x2, xw[a].y) - __builtin_bit_cast(f16x2, yw[b].y));
          h += habs2(__builtin_bit_cast(f16x2, xw[a].z) - __builtin_bit_cast(f16x2, yw[b].z));
          h += habs2(__builtin_bit_cast(f16x2, xw[a].w) - __builtin_bit_cast(f16x2, yw[b].w));
          hacc[a][b] = h;
        }
    }
    // flush group to f32
#pragma unroll
    for (int a = 0; a < 2; ++a)
#pragma unroll
      for (int b = 0; b < 4; ++b)
        acc4[a][b] += (float)hacc[a][b].x + (float)hacc[a][b].y;
  }

  // store S tile (f32)
#pragma unroll
  for (int a = 0; a < 2; ++a) {
    int i = i0 + ty + a * 16;
#pragma unroll
    for (int b = 0; b < 4; ++b) {
      int j = j0 + tx + b * 16;
      S[(size_t)i * MM + j] = -acc4[a][b];
    }
  }

  // row partials
#pragma unroll
  for (int a = 0; a < 2; ++a) {
    float m = -acc4[a][0];
#pragma unroll
    for (int b = 1; b < 4; ++b) m = fmaxf(m, -acc4[a][b]);
    float s = 0.f;
#pragma unroll
    for (int b = 0; b < 4; ++b) s += __expf(-acc4[a][b] - m);
#pragma unroll
    for (int off = 1; off < 16; off <<= 1) {
      float m2 = __shfl_xor(m, off, 64);
      float s2 = __shfl_xor(s, off, 64);
      merge_ms(m, s, m2, s2);
    }
    if (tx == 0) {
      int i = i0 + ty + a * 16;
      rowPM[(size_t)jt * NN + i] = m;
      rowPS[(size_t)jt * NN + i] = s;
    }
  }

  // col partials
#pragma unroll
  for (int b = 0; b < 4; ++b) {
    int c = tx + b * 16;
    float m = fmaxf(-acc4[0][b], -acc4[1][b]);
    float s = __expf(-acc4[0][b] - m) + __expf(-acc4[1][b] - m);
    lm[ty][c] = m;
    lsv[ty][c] = s;
  }
  __syncthreads();
  if (t < 64) {
    float m = lm[0][t], s = lsv[0][t];
#pragma unroll
    for (int k = 1; k < 16; ++k) merge_ms(m, s, lm[k][t], lsv[k][t]);
    colPM[(size_t)it * MM + j0 + t] = m;
    colPS[(size_t)it * MM + j0 + t] = s;
  }
}

// ---- K2: merge stripe partials -> global stats (R15 EXACT) ----
__global__ __launch_bounds__(256) void k_merge(const float* __restrict__ rowPM,
                                               const float* __restrict__ rowPS,
                                               const float* __restrict__ colPM,
                                               const float* __restrict__ colPS,
                                               float* __restrict__ rowM,
                                               float* __restrict__ rowS,
                                               float* __restrict__ colM,
                                               float* __restrict__ colS) {
  int g = blockIdx.x * 256 + threadIdx.x;
  if (g < NN) {
    float m = rowPM[g], s = rowPS[g];
#pragma unroll
    for (int k = 1; k < NTJ; ++k)
      merge_ms(m, s, rowPM[(size_t)k * NN + g], rowPS[(size_t)k * NN + g]);
    rowM[g] = m;
    rowS[g] = s;
  } else {
    int c = g - NN;
    float m = colPM[c], s = colPS[c];
#pragma unroll
    for (int k = 1; k < NTI; ++k)
      merge_ms(m, s, colPM[(size_t)k * MM + c], colPS[(size_t)k * MM + c]);
    colM[c] = m;
    colS[c] = s;
  }
}

// ---- K3: weighted accumulation, 256 blocks x 4 rows (R15 EXACT) ----
__global__ __launch_bounds__(256) void k_accum(const float* __restrict__ S,
                                               const float* __restrict__ rowM,
                                               const float* __restrict__ rowS,
                                               const float* __restrict__ colM,
                                               const float* __restrict__ colS,
                                               float* __restrict__ bNum,
                                               float* __restrict__ bDen) {
  const int bid = blockIdx.x;  // rows [bid*4, bid*4+4)
  const int t = threadIdx.x;

  float4 cm = reinterpret_cast<const float4*>(colM)[t];
  float4 cs = reinterpret_cast<const float4*>(colS)[t];
  float4 ci;
  ci.x = 1.f / cs.x; ci.y = 1.f / cs.y; ci.z = 1.f / cs.z; ci.w = 1.f / cs.w;

  __shared__ float rowMl[4], rowIl[4];
  if (t < 4) {
    int r = bid * 4 + t;
    rowMl[t] = rowM[r];
    rowIl[t] = 1.f / rowS[r];
  }
  __syncthreads();

  float num = 0.f, den = 0.f;
#pragma unroll
  for (int rl = 0; rl < 4; ++rl) {
    int row = bid * 4 + rl;
    float4 v = reinterpret_cast<const float4*>(S + (size_t)row * MM)[t];
    float rm = rowMl[rl], ri = rowIl[rl];
#define DO_COMP(VX, CMX, CIX)                 \
    {                                         \
      float a = __expf((VX) - rm) * ri;       \
      float b = __expf((VX) - (CMX)) * (CIX); \
      float w = a + b - a * b;                \
      num += w * (VX);                        \
      den += w;                               \
    }
    DO_COMP(v.x, cm.x, ci.x)
    DO_COMP(v.y, cm.y, ci.y)
    DO_COMP(v.z, cm.z, ci.z)
    DO_COMP(v.w, cm.w, ci.w)
#undef DO_COMP
  }

  num = wredSum(num);
  den = wredSum(den);
  __shared__ float rn[4], rd[4];
  const int lane = t & 63, wv = t >> 6;
  if (lane == 0) { rn[wv] = num; rd[wv] = den; }
  __syncthreads();
  if (t == 0) {
    bNum[bid] = rn[0] + rn[1] + rn[2] + rn[3];
    bDen[bid] = rd[0] + rd[1] + rd[2] + rd[3];
  }
}

// ---- K4: final reduce + divide (R15 EXACT) ----
__global__ __launch_bounds__(256) void k_final(const float* __restrict__ bNum,
                                               const float* __restrict__ bDen,
                                               float* __restrict__ out) {
  const int t = threadIdx.x;
  float n = bNum[t];
  float d = bDen[t];
  n = wredSum(n);
  d = wredSum(d);
  __shared__ float rn[4], rd[4];
  const int lane = t & 63, wv = t >> 6;
  if (lane == 0) { rn[wv] = n; rd[wv] = d; }
  __syncthreads();
  if (t == 0) out[0] = (rn[0] + rn[1] + rn[2] + rn[3]) / (rd[0] + rd[1] + rd[2] + rd[3]);
}

// ---------------- launch ----------------
extern "C" void kernel_launch(void* const* d_in, const int* in_sizes, int n_in,
                              void* d_out, int out_size, void* d_ws, size_t ws_size,
                              hipStream_t stream) {
  const float* zx = (const float*)d_in[0];
  const float* zy = (const float*)d_in[1];
  float* out = (float*)d_out;

  float* ws = (float*)d_ws;
  float* S     = ws;                        // 1M floats
  float* rowPM = S + (size_t)NN * MM;       // NTJ x NN
  float* rowPS = rowPM + NTJ * NN;
  float* colPM = rowPS + NTJ * NN;          // NTI x MM
  float* colPS = colPM + NTI * MM;
  float* rowM  = colPS + NTI * MM;
  float* rowS  = rowM + NN;
  float* colM  = rowS + NN;
  float* colS  = colM + MM;
  float* bNum  = colS + MM;                 // 256
  float* bDen  = bNum + 256;                // 256

  k_tile<<<dim3(NTJ, NTI), 256, 0, stream>>>(zx, zy, S, rowPM, rowPS, colPM, colPS);
  k_merge<<<8, 256, 0, stream>>>(rowPM, rowPS, colPM, colPS, rowM, rowS, colM, colS);
  k_accum<<<256, 256, 0, stream>>>(S, rowM, rowS, colM, colS, bNum, bDen);
  k_final<<<1, 256, 0, stream>>>(bNum, bDen, out);
}

// Round 17
// 32.218 us; speedup vs baseline: 1.0450x; 1.0450x over previous
//
#include <hip/hip_runtime.h>
#include <math.h>

#define NN 1024
#define MM 1024
#define DD 256
#define TI 32          // i-rows per block
#define TJ 64          // j-cols per block
#define NTI 32         // i-tiles (col-partial stripes)
#define NTJ 16         // j-tiles (row-partial stripes)
#define PITCH_H 264    // f16 pitch (528 B/row)

typedef _Float16 f16x2 __attribute__((ext_vector_type(2)));
typedef _Float16 f16x4 __attribute__((ext_vector_type(4)));

__device__ inline f16x2 habs2(f16x2 v) {
  unsigned u = __builtin_bit_cast(unsigned, v) & 0x7FFF7FFFu;
  return __builtin_bit_cast(f16x2, u);
}

__device__ inline float dot2acc(f16x2 a, float acc) {
#if __has_builtin(__builtin_amdgcn_fdot2)
  const f16x2 one = {(_Float16)1.0f, (_Float16)1.0f};
  return __builtin_amdgcn_fdot2(a, one, acc, false);
#else
  return acc + (float)a.x + (float)a.y;
#endif
}

__device__ inline void merge_ms(float& m, float& s, float m2, float s2) {
  float mn = fmaxf(m, m2);
  s = s * __expf(m - mn) + s2 * __expf(m2 - mn);
  m = mn;
}

__device__ inline float wredSum(float v) {
#pragma unroll
  for (int o = 32; o > 0; o >>= 1) v += __shfl_down(v, o, 64);
  return v;
}

// ---- K1: f16 distance, 32x64 tile, 512 blocks (2/CU, 8 waves/CU) ----
__global__ __launch_bounds__(256) void k_tile(const float* __restrict__ zx,
                                              const float* __restrict__ zy,
                                              float* __restrict__ S,
                                              float* __restrict__ rowPM,
                                              float* __restrict__ rowPS,
                                              float* __restrict__ colPM,
                                              float* __restrict__ colPS) {
  __shared__ __align__(16) _Float16 xs[TI * PITCH_H];  // 16.5 KiB
  __shared__ __align__(16) _Float16 ys[TJ * PITCH_H];  // 33 KiB
  __shared__ float lm[16][64];
  __shared__ float lsv[16][64];

  const int it = blockIdx.y, jt = blockIdx.x;   // it in [0,32), jt in [0,16)
  const int i0 = it * TI, j0 = jt * TJ;
  const int t = threadIdx.x;
  const int tx = t & 15, ty = t >> 4;

  // stage x: 32 rows x 256 f32 -> f16
#pragma unroll
  for (int k = 0; k < 8; ++k) {
    int idx4 = t + k * 256;
    int r = idx4 >> 6;
    int c4 = idx4 & 63;
    float4 v = reinterpret_cast<const float4*>(zx + (size_t)(i0 + r) * DD)[c4];
    f16x4 h = {(_Float16)v.x, (_Float16)v.y, (_Float16)v.z, (_Float16)v.w};
    *reinterpret_cast<f16x4*>(&xs[r * PITCH_H + c4 * 4]) = h;
  }
  // stage y: 64 rows x 256 f32 -> f16
#pragma unroll
  for (int k = 0; k < 16; ++k) {
    int idx4 = t + k * 256;
    int r = idx4 >> 6;
    int c4 = idx4 & 63;
    float4 v = reinterpret_cast<const float4*>(zy + (size_t)(j0 + r) * DD)[c4];
    f16x4 h = {(_Float16)v.x, (_Float16)v.y, (_Float16)v.z, (_Float16)v.w};
    *reinterpret_cast<f16x4*>(&ys[r * PITCH_H + c4 * 4]) = h;
  }
  __syncthreads();

  float acc4[2][4] = {{0.f}};
  for (int s8 = 0; s8 < 32; ++s8) {
    uint4 xw[2], yw[4];
#pragma unroll
    for (int a = 0; a < 2; ++a)
      xw[a] = *reinterpret_cast<const uint4*>(&xs[(ty + a * 16) * PITCH_H + s8 * 8]);
#pragma unroll
    for (int b = 0; b < 4; ++b)
      yw[b] = *reinterpret_cast<const uint4*>(&ys[(tx + b * 16) * PITCH_H + s8 * 8]);
#pragma unroll
    for (int a = 0; a < 2; ++a)
#pragma unroll
      for (int b = 0; b < 4; ++b) {
        float acc = acc4[a][b];
        acc = dot2acc(habs2(__builtin_bit_cast(f16x2, xw[a].x) - __builtin_bit_cast(f16x2, yw[b].x)), acc);
        acc = dot2acc(habs2(__builtin_bit_cast(f16x2, xw[a].y) - __builtin_bit_cast(f16x2, yw[b].y)), acc);
        acc = dot2acc(habs2(__builtin_bit_cast(f16x2, xw[a].z) - __builtin_bit_cast(f16x2, yw[b].z)), acc);
        acc = dot2acc(habs2(__builtin_bit_cast(f16x2, xw[a].w) - __builtin_bit_cast(f16x2, yw[b].w)), acc);
        acc4[a][b] = acc;
      }
  }

  // store S tile (f32)
#pragma unroll
  for (int a = 0; a < 2; ++a) {
    int i = i0 + ty + a * 16;
#pragma unroll
    for (int b = 0; b < 4; ++b) {
      int j = j0 + tx + b * 16;
      S[(size_t)i * MM + j] = -acc4[a][b];
    }
  }

  // row partials
#pragma unroll
  for (int a = 0; a < 2; ++a) {
    float m = -acc4[a][0];
#pragma unroll
    for (int b = 1; b < 4; ++b) m = fmaxf(m, -acc4[a][b]);
    float s = 0.f;
#pragma unroll
    for (int b = 0; b < 4; ++b) s += __expf(-acc4[a][b] - m);
#pragma unroll
    for (int off = 1; off < 16; off <<= 1) {
      float m2 = __shfl_xor(m, off, 64);
      float s2 = __shfl_xor(s, off, 64);
      merge_ms(m, s, m2, s2);
    }
    if (tx == 0) {
      int i = i0 + ty + a * 16;
      rowPM[(size_t)jt * NN + i] = m;
      rowPS[(size_t)jt * NN + i] = s;
    }
  }

  // col partials
#pragma unroll
  for (int b = 0; b < 4; ++b) {
    int c = tx + b * 16;
    float m = fmaxf(-acc4[0][b], -acc4[1][b]);
    float s = __expf(-acc4[0][b] - m) + __expf(-acc4[1][b] - m);
    lm[ty][c] = m;
    lsv[ty][c] = s;
  }
  __syncthreads();
  if (t < 64) {
    float m = lm[0][t], s = lsv[0][t];
#pragma unroll
    for (int k = 1; k < 16; ++k) merge_ms(m, s, lm[k][t], lsv[k][t]);
    colPM[(size_t)it * MM + j0 + t] = m;
    colPS[(size_t)it * MM + j0 + t] = s;
  }
}

// ---- K2: merge stripe partials -> global stats ----
__global__ __launch_bounds__(256) void k_merge(const float* __restrict__ rowPM,
                                               const float* __restrict__ rowPS,
                                               const float* __restrict__ colPM,
                                               const float* __restrict__ colPS,
                                               float* __restrict__ rowM,
                                               float* __restrict__ rowS,
                                               float* __restrict__ colM,
                                               float* __restrict__ colS) {
  int g = blockIdx.x * 256 + threadIdx.x;
  if (g < NN) {
    float m = rowPM[g], s = rowPS[g];
#pragma unroll
    for (int k = 1; k < NTJ; ++k)
      merge_ms(m, s, rowPM[(size_t)k * NN + g], rowPS[(size_t)k * NN + g]);
    rowM[g] = m;
    rowS[g] = s;
  } else {
    int c = g - NN;
    float m = colPM[c], s = colPS[c];
#pragma unroll
    for (int k = 1; k < NTI; ++k)
      merge_ms(m, s, colPM[(size_t)k * MM + c], colPS[(size_t)k * MM + c]);
    colM[c] = m;
    colS[c] = s;
  }
}

// ---- K3: weighted accumulation, 256 blocks x 4 rows, PRE-MERGED stats ----
__global__ __launch_bounds__(256) void k_accum(const float* __restrict__ S,
                                               const float* __restrict__ rowM,
                                               const float* __restrict__ rowS,
                                               const float* __restrict__ colM,
                                               const float* __restrict__ colS,
                                               float* __restrict__ bNum,
                                               float* __restrict__ bDen) {
  const int bid = blockIdx.x;  // rows [bid*4, bid*4+4)
  const int t = threadIdx.x;

  float4 cm = reinterpret_cast<const float4*>(colM)[t];
  float4 cs = reinterpret_cast<const float4*>(colS)[t];
  float4 ci;
  ci.x = 1.f / cs.x; ci.y = 1.f / cs.y; ci.z = 1.f / cs.z; ci.w = 1.f / cs.w;

  __shared__ float rowMl[4], rowIl[4];
  if (t < 4) {
    int r = bid * 4 + t;
    rowMl[t] = rowM[r];
    rowIl[t] = 1.f / rowS[r];
  }
  __syncthreads();

  float num = 0.f, den = 0.f;
#pragma unroll
  for (int rl = 0; rl < 4; ++rl) {
    int row = bid * 4 + rl;
    float4 v = reinterpret_cast<const float4*>(S + (size_t)row * MM)[t];
    float rm = rowMl[rl], ri = rowIl[rl];
#define DO_COMP(VX, CMX, CIX)                 \
    {                                         \
      float a = __expf((VX) - rm) * ri;       \
      float b = __expf((VX) - (CMX)) * (CIX); \
      float w = a + b - a * b;                \
      num += w * (VX);                        \
      den += w;                               \
    }
    DO_COMP(v.x, cm.x, ci.x)
    DO_COMP(v.y, cm.y, ci.y)
    DO_COMP(v.z, cm.z, ci.z)
    DO_COMP(v.w, cm.w, ci.w)
#undef DO_COMP
  }

  num = wredSum(num);
  den = wredSum(den);
  __shared__ float rn[4], rd[4];
  const int lane = t & 63, wv = t >> 6;
  if (lane == 0) { rn[wv] = num; rd[wv] = den; }
  __syncthreads();
  if (t == 0) {
    bNum[bid] = rn[0] + rn[1] + rn[2] + rn[3];
    bDen[bid] = rd[0] + rd[1] + rd[2] + rd[3];
  }
}

// ---- K4: final reduce + divide ----
__global__ __launch_bounds__(256) void k_final(const float* __restrict__ bNum,
                                               const float* __restrict__ bDen,
                                               float* __restrict__ out) {
  const int t = threadIdx.x;
  float n = bNum[t];
  float d = bDen[t];
  n = wredSum(n);
  d = wredSum(d);
  __shared__ float rn[4], rd[4];
  const int lane = t & 63, wv = t >> 6;
  if (lane == 0) { rn[wv] = n; rd[wv] = d; }
  __syncthreads();
  if (t == 0) out[0] = (rn[0] + rn[1] + rn[2] + rn[3]) / (rd[0] + rd[1] + rd[2] + rd[3]);
}

// ---------------- launch ----------------
extern "C" void kernel_launch(void* const* d_in, const int* in_sizes, int n_in,
                              void* d_out, int out_size, void* d_ws, size_t ws_size,
                              hipStream_t stream) {
  const float* zx = (const float*)d_in[0];
  const float* zy = (const float*)d_in[1];
  float* out = (float*)d_out;

  float* ws = (float*)d_ws;
  float* S     = ws;                        // 1M floats
  float* rowPM = S + (size_t)NN * MM;       // NTJ x NN
  float* rowPS = rowPM + NTJ * NN;
  float* colPM = rowPS + NTJ * NN;          // NTI x MM
  float* colPS = colPM + NTI * MM;
  float* rowM  = colPS + NTI * MM;
  float* rowS  = rowM + NN;
  float* colM  = rowS + NN;
  float* colS  = colM + MM;
  float* bNum  = colS + MM;                 // 256
  float* bDen  = bNum + 256;                // 256

  k_tile<<<dim3(NTJ, NTI), 256, 0, stream>>>(zx, zy, S, rowPM, rowPS, colPM, colPS);
  k_merge<<<8, 256, 0, stream>>>(rowPM, rowPS, colPM, colPS, rowM, rowS, colM, colS);
  k_accum<<<256, 256, 0, stream>>>(S, rowM, rowS, colM, colS, bNum, bDen);
  k_final<<<1, 256, 0, stream>>>(bNum, bDen, out);
}